// Round 7
// baseline (286.437 us; speedup 1.0000x reference)
//
#include <hip/hip_runtime.h>
#include <math.h>

#define B_  4
#define V_  256
#define C1_ 64
#define C2_ 32
#define H0_ 128
#define H2_ 256

typedef short bf16x8 __attribute__((ext_vector_type(8)));
typedef short bf16x4 __attribute__((ext_vector_type(4)));
typedef float f32x4  __attribute__((ext_vector_type(4)));

static __device__ __forceinline__ short f2bf(float f) {
    unsigned u = __float_as_uint(f);
    u += 0x7fffu + ((u >> 16) & 1u);          // RNE
    return (short)(u >> 16);
}

// ---------------------------------------------------------------------------
// Prep (K1, blocks >= 256): bf16+transpose MFMA weight fragments, and fp32
// transposed copies for the per-node fused tails.
//  wsW (shorts): W1cT1[4096] | W2T1[16384] | W1cT2[4096] | W2T2[16384]
//  WPT[n][k] = W1a2[k][n]-W1b2[k][n]; WQT[n][k] = W1b2[k][n]   (128x128)
//  WJT[n][k] = W3[k][n]; WIT[n][k] = W3[128+k][n]              (256x128)
// ---------------------------------------------------------------------------
static __device__ void prep_dev(int idx,
    const float* __restrict__ W1c1, const float* __restrict__ W21,
    const float* __restrict__ W1c2, const float* __restrict__ W22,
    const float* __restrict__ Wc2,  const float* __restrict__ W3,
    short* __restrict__ wsW, float* __restrict__ WPT, float* __restrict__ WQT,
    float* __restrict__ WJT, float* __restrict__ WIT)
{
    if (idx < 4096) {
        int n = idx >> 5, k = idx & 31;
        wsW[idx] = f2bf(W1c1[k * H0_ + n]);
    } else if (idx < 20480) {
        int t = idx - 4096; int n = t >> 7, k = t & 127;
        wsW[idx] = f2bf(W21[k * H0_ + n]);
    } else if (idx < 24576) {
        int t = idx - 20480; int n = t >> 5, k = t & 31;
        wsW[idx] = f2bf(W1c2[k * H0_ + n]);
    } else if (idx < 40960) {
        int t = idx - 24576; int n = t >> 7, k = t & 127;
        wsW[idx] = f2bf(W22[k * H0_ + n]);
    } else if (idx < 57344) {
        int t = idx - 40960; int n = t >> 7, k = t & 127;
        WPT[t] = Wc2[k * H0_ + n] - Wc2[(H0_ + k) * H0_ + n];
    } else if (idx < 73728) {
        int t = idx - 57344; int n = t >> 7, k = t & 127;
        WQT[t] = Wc2[(H0_ + k) * H0_ + n];
    } else if (idx < 106496) {
        int t = idx - 73728; int n = t >> 7, k = t & 127;
        WJT[t] = W3[k * H2_ + n];
    } else if (idx < 139264) {
        int t = idx - 106496; int n = t >> 7, k = t & 127;
        WIT[t] = W3[(H0_ + k) * H2_ + n];
    }
}

// ---------------------------------------------------------------------------
// Conv1 hoist, 4 nodes/block: P1 = x@(W1a-W1b)+b1, Q1 = x@W1b.
// ---------------------------------------------------------------------------
template <int CIN>
static __device__ void node_pre4(int g,
    const float* __restrict__ x, const float* __restrict__ W1,
    const float* __restrict__ b1, float* __restrict__ P, float* __restrict__ Q)
{
    const int bi0 = g * 4;
    const int tid = threadIdx.x;
    const int n   = tid & 127;
    const bool isP = tid < 128;             // wave-uniform split

    __shared__ __align__(16) float s_x4[4][CIN];
    for (int idx = tid; idx < 4 * CIN; idx += 256)
        s_x4[idx / CIN][idx % CIN] = x[bi0 * CIN + idx];
    __syncthreads();

    float acc[4];
    float binit = isP ? b1[n] : 0.f;
    #pragma unroll
    for (int nd = 0; nd < 4; ++nd) acc[nd] = binit;

    for (int k = 0; k < CIN; k += 4) {
        float4 wv;
        if (isP) {
            wv.x = W1[(k + 0) * H0_ + n] - W1[(CIN + k + 0) * H0_ + n];
            wv.y = W1[(k + 1) * H0_ + n] - W1[(CIN + k + 1) * H0_ + n];
            wv.z = W1[(k + 2) * H0_ + n] - W1[(CIN + k + 2) * H0_ + n];
            wv.w = W1[(k + 3) * H0_ + n] - W1[(CIN + k + 3) * H0_ + n];
        } else {
            wv.x = W1[(CIN + k + 0) * H0_ + n];
            wv.y = W1[(CIN + k + 1) * H0_ + n];
            wv.z = W1[(CIN + k + 2) * H0_ + n];
            wv.w = W1[(CIN + k + 3) * H0_ + n];
        }
        #pragma unroll
        for (int nd = 0; nd < 4; ++nd) {
            float4 xv = *reinterpret_cast<const float4*>(&s_x4[nd][k]);
            acc[nd] = fmaf(xv.x, wv.x, acc[nd]);
            acc[nd] = fmaf(xv.y, wv.y, acc[nd]);
            acc[nd] = fmaf(xv.z, wv.z, acc[nd]);
            acc[nd] = fmaf(xv.w, wv.w, acc[nd]);
        }
    }
    float* dst = isP ? P : Q;
    #pragma unroll
    for (int nd = 0; nd < 4; ++nd)
        dst[(bi0 + nd) * H0_ + n] = acc[nd];
}

__global__ __launch_bounds__(256) void pre1_k(
    const float* __restrict__ xf, const float* __restrict__ ec1W1,
    const float* __restrict__ ec1b1, float* __restrict__ P1, float* __restrict__ Q1,
    const float* __restrict__ W1c1, const float* __restrict__ W21,
    const float* __restrict__ W1c2, const float* __restrict__ W22,
    const float* __restrict__ Wc2,  const float* __restrict__ W3,
    short* __restrict__ wsW, float* __restrict__ WPT, float* __restrict__ WQT,
    float* __restrict__ WJT, float* __restrict__ WIT)
{
    if (blockIdx.x < 256)
        node_pre4<C1_>(blockIdx.x, xf, ec1W1, ec1b1, P1, Q1);
    else
        prep_dev((blockIdx.x - 256) * 256 + threadIdx.x,
                 W1c1, W21, W1c2, W22, Wc2, W3, wsW, WPT, WQT, WJT, WIT);
}

// ---------------------------------------------------------------------------
// Dense EdgeConvE for ONE node; result (post max+bias+relu) in s_x[128].
// 4 waves; 4 chunks of 64 edges. Double-buffered s_h1 -> ONE barrier per
// chunk. Next chunk's e prefetched into regs right after the barrier so the
// L2 latency hides under GEMM2's 32 MFMAs. P reloaded per chunk (L1-hot)
// to keep VGPR <= 128 for 4 blocks/CU.
// ---------------------------------------------------------------------------
static __device__ void conv_node(int bi,
    const int* __restrict__ adj, const float* __restrict__ e,
    const float* __restrict__ P, const float* __restrict__ Q,
    const short* __restrict__ W1cT, const short* __restrict__ W2T,
    const float* __restrict__ b2,
    short (*s_h1)[64][136], float* s_x)
{
    const int b    = bi >> 8;
    const int tid  = threadIdx.x;
    const int w    = tid >> 6;
    const int lane = tid & 63;
    const int l15  = lane & 15;
    const int quad = lane >> 4;

    // persistent: GEMM2 B-fragments for this wave's 2 N-tiles (32 VGPRs)
    bf16x8 B2[2][4];
    #pragma unroll
    for (int t = 0; t < 2; ++t)
        #pragma unroll
        for (int kk = 0; kk < 4; ++kk)
            B2[t][kk] = *(const bf16x8*)(W2T + ((2 * w + t) * 16 + l15) * H0_ + kk * 32 + quad * 8);

    float vmax[2] = {-1e30f, -1e30f};

    const float* __restrict__ ebase = e + (size_t)bi * V_ * C2_;
    const float* __restrict__ Pr    = P + bi * H0_;

    // prefetch chunk 0's e
    float4 e0 = *(const float4*)(ebase + (w * 16 + l15) * C2_ + quad * 8);
    float4 e1 = *(const float4*)(ebase + (w * 16 + l15) * C2_ + quad * 8 + 4);

    for (int c = 0; c < 4; ++c) {
        // ---- GEMM1: this wave's 16 edges -> h1 rows in buf[c&1] ----
        bf16x8 Bf;
        Bf[0] = f2bf(e0.x); Bf[1] = f2bf(e0.y); Bf[2] = f2bf(e0.z); Bf[3] = f2bf(e0.w);
        Bf[4] = f2bf(e1.x); Bf[5] = f2bf(e1.y); Bf[6] = f2bf(e1.z); Bf[7] = f2bf(e1.w);

        const int jr = c * 64 + w * 16 + l15;
        const float* __restrict__ Qr = Q + (b * V_ + jr) * H0_;
        short* __restrict__ dst = &s_h1[c & 1][w * 16 + l15][0];
        #pragma unroll
        for (int nt = 0; nt < 8; ++nt) {
            bf16x8 A1 = *(const bf16x8*)(W1cT + (nt * 16 + l15) * C2_ + quad * 8);
            f32x4 c4 = *(const f32x4*)(Pr + nt * 16 + quad * 4)
                     + *(const f32x4*)(Qr + nt * 16 + quad * 4);
            f32x4 a = __builtin_amdgcn_mfma_f32_16x16x32_bf16(A1, Bf, c4, 0, 0, 0);
            bf16x4 hv;
            hv[0] = f2bf(fmaxf(a[0], 0.f));
            hv[1] = f2bf(fmaxf(a[1], 0.f));
            hv[2] = f2bf(fmaxf(a[2], 0.f));
            hv[3] = f2bf(fmaxf(a[3], 0.f));
            *(bf16x4*)(dst + nt * 16 + quad * 4) = hv;
        }
        __syncthreads();                     // the only barrier per chunk

        // prefetch next chunk's e (hides under GEMM2)
        if (c < 3) {
            const int jn = (c + 1) * 64 + w * 16 + l15;
            e0 = *(const float4*)(ebase + jn * C2_ + quad * 8);
            e1 = *(const float4*)(ebase + jn * C2_ + quad * 8 + 4);
        }

        // ---- GEMM2: this wave's 2 N-tiles over all 64 staged rows ----
        const short (* __restrict__ buf)[136] = s_h1[c & 1];
        #pragma unroll
        for (int m = 0; m < 4; ++m) {
            const int4 av = *(const int4*)(adj + bi * V_ + c * 64 + m * 16 + quad * 4);
            f32x4 acc0 = {0.f, 0.f, 0.f, 0.f}, acc1 = {0.f, 0.f, 0.f, 0.f};
            #pragma unroll
            for (int kk = 0; kk < 4; ++kk) {
                bf16x8 A2 = *(const bf16x8*)(&buf[m * 16 + l15][kk * 32 + quad * 8]);
                acc0 = __builtin_amdgcn_mfma_f32_16x16x32_bf16(A2, B2[0][kk], acc0, 0, 0, 0);
                acc1 = __builtin_amdgcn_mfma_f32_16x16x32_bf16(A2, B2[1][kk], acc1, 0, 0, 0);
            }
            float m00 = av.x > 0 ? acc0[0] : -1e30f;
            float m01 = av.y > 0 ? acc0[1] : -1e30f;
            float m02 = av.z > 0 ? acc0[2] : -1e30f;
            float m03 = av.w > 0 ? acc0[3] : -1e30f;
            vmax[0] = fmaxf(vmax[0], fmaxf(fmaxf(m00, m01), fmaxf(m02, m03)));
            float m10 = av.x > 0 ? acc1[0] : -1e30f;
            float m11 = av.y > 0 ? acc1[1] : -1e30f;
            float m12 = av.z > 0 ? acc1[2] : -1e30f;
            float m13 = av.w > 0 ? acc1[3] : -1e30f;
            vmax[1] = fmaxf(vmax[1], fmaxf(fmaxf(m10, m11), fmaxf(m12, m13)));
        }
        // no trailing barrier: next chunk writes the other buffer
    }

    // cross-quad max; bias+relu; each wave owns its 2 N-tiles (no cross-wave)
    #pragma unroll
    for (int t = 0; t < 2; ++t) {
        float p = vmax[t];
        p = fmaxf(p, __shfl_xor(p, 16, 64));
        p = fmaxf(p, __shfl_xor(p, 32, 64));
        if (quad == 0) {
            const int n = (2 * w + t) * 16 + l15;
            s_x[n] = fmaxf(p + b2[n], 0.f);  // isolated node -> 0
        }
    }
    __syncthreads();
}

// ---------------------------------------------------------------------------
// Conv1 + fused conv2-hoist tail: P2 = x1@(W1a2-W1b2)+b1_2, Q2 = x1@W1b2.
// Thread t<128 -> P2 col t (full K), t>=128 -> Q2 col t-128 (full K).
// ---------------------------------------------------------------------------
__global__ __launch_bounds__(256, 4) void conv1_k(
    const int* __restrict__ adj, const float* __restrict__ e,
    const float* __restrict__ P1, const float* __restrict__ Q1,
    const short* __restrict__ W1cT, const short* __restrict__ W2T,
    const float* __restrict__ b2,
    const float* __restrict__ WPT, const float* __restrict__ WQT,
    const float* __restrict__ b1_2,
    float* __restrict__ P2, float* __restrict__ Q2)
{
    __shared__ __align__(16) short s_h1[2][64][136];
    __shared__ __align__(16) float s_x[H0_];

    const int bi = blockIdx.x;
    conv_node(bi, adj, e, P1, Q1, W1cT, W2T, b2, s_h1, s_x);

    const int tid = threadIdx.x, n = tid & 127;
    const bool isP = tid < 128;
    const float* wrow = (isP ? WPT : WQT) + n * H0_;
    float acc = isP ? b1_2[n] : 0.f;
    #pragma unroll 4
    for (int k = 0; k < H0_; k += 4) {
        float4 x = *(const float4*)(s_x + k);
        float4 a = *(const float4*)(wrow + k);
        acc = fmaf(x.x, a.x, acc);
        acc = fmaf(x.y, a.y, acc);
        acc = fmaf(x.z, a.z, acc);
        acc = fmaf(x.w, a.w, acc);
    }
    if (isP) P2[bi * H0_ + n] = acc;
    else     Q2[bi * H0_ + n] = acc;
}

// ---------------------------------------------------------------------------
// Conv2 + fused pair-hoist tail: Ai = x2@W3[H0:]+b3, Aj = x2@W3[:H0].
// ---------------------------------------------------------------------------
__global__ __launch_bounds__(256, 4) void conv2_k(
    const int* __restrict__ adj, const float* __restrict__ e,
    const float* __restrict__ P2, const float* __restrict__ Q2,
    const short* __restrict__ W1cT, const short* __restrict__ W2T,
    const float* __restrict__ b2,
    const float* __restrict__ WJT, const float* __restrict__ WIT,
    const float* __restrict__ b3,
    float* __restrict__ Ai, float* __restrict__ Aj)
{
    __shared__ __align__(16) short s_h1[2][64][136];
    __shared__ __align__(16) float s_x[H0_];

    const int bi = blockIdx.x;
    conv_node(bi, adj, e, P2, Q2, W1cT, W2T, b2, s_h1, s_x);

    const int n = threadIdx.x;                 // 0..255
    float aI = b3[n], aJ = 0.f;
    const float* wj = WJT + n * H0_;
    const float* wi = WIT + n * H0_;
    #pragma unroll 4
    for (int k = 0; k < H0_; k += 4) {
        float4 x  = *(const float4*)(s_x + k);
        float4 vj = *(const float4*)(wj + k);
        float4 vi = *(const float4*)(wi + k);
        aJ = fmaf(x.x, vj.x, aJ);  aI = fmaf(x.x, vi.x, aI);
        aJ = fmaf(x.y, vj.y, aJ);  aI = fmaf(x.y, vi.y, aI);
        aJ = fmaf(x.z, vj.z, aJ);  aI = fmaf(x.z, vi.z, aI);
        aJ = fmaf(x.w, vj.w, aJ);  aI = fmaf(x.w, vi.w, aI);
    }
    Ai[bi * H2_ + n] = aI;
    Aj[bi * H2_ + n] = aJ;
}

// ---------------------------------------------------------------------------
// Pair output: block = 4 i's, wave = one i, lane=(jj,c): f = relu(Ai+Aj),
// z = f.Wo -> sigmoid.
// ---------------------------------------------------------------------------
__global__ __launch_bounds__(256) void pair_out_k(
    const float* __restrict__ Ai, const float* __restrict__ Aj,
    const float* __restrict__ Wo, const float* __restrict__ bo,
    float* __restrict__ out)
{
    const int blk  = blockIdx.x;
    const int b    = blk >> 6;
    const int i    = ((blk & 63) << 2) + (threadIdx.x >> 6);
    const int lane = threadIdx.x & 63;
    const int jj   = lane >> 4;
    const int c    = lane & 15;

    const float* ai = Ai + (b * V_ + i) * H2_ + c * 16;
    float4 a0 = *(const float4*)(ai);
    float4 a1 = *(const float4*)(ai + 4);
    float4 a2 = *(const float4*)(ai + 8);
    float4 a3 = *(const float4*)(ai + 12);
    const float* wo = Wo + c * 16;
    float4 w0 = *(const float4*)(wo);
    float4 w1 = *(const float4*)(wo + 4);
    float4 w2 = *(const float4*)(wo + 8);
    float4 w3 = *(const float4*)(wo + 12);
    const float bo0 = bo[0];

    for (int j0 = 0; j0 < V_; j0 += 4) {
        const int j = j0 + jj;
        const float* aj = Aj + (b * V_ + j) * H2_ + c * 16;
        float4 q0 = *(const float4*)(aj);
        float4 q1 = *(const float4*)(aj + 4);
        float4 q2 = *(const float4*)(aj + 8);
        float4 q3 = *(const float4*)(aj + 12);
        float p;
        p = fmaxf(a0.x + q0.x, 0.f) * w0.x;
        p = fmaf(fmaxf(a0.y + q0.y, 0.f), w0.y, p);
        p = fmaf(fmaxf(a0.z + q0.z, 0.f), w0.z, p);
        p = fmaf(fmaxf(a0.w + q0.w, 0.f), w0.w, p);
        p = fmaf(fmaxf(a1.x + q1.x, 0.f), w1.x, p);
        p = fmaf(fmaxf(a1.y + q1.y, 0.f), w1.y, p);
        p = fmaf(fmaxf(a1.z + q1.z, 0.f), w1.z, p);
        p = fmaf(fmaxf(a1.w + q1.w, 0.f), w1.w, p);
        p = fmaf(fmaxf(a2.x + q2.x, 0.f), w2.x, p);
        p = fmaf(fmaxf(a2.y + q2.y, 0.f), w2.y, p);
        p = fmaf(fmaxf(a2.z + q2.z, 0.f), w2.z, p);
        p = fmaf(fmaxf(a2.w + q2.w, 0.f), w2.w, p);
        p = fmaf(fmaxf(a3.x + q3.x, 0.f), w3.x, p);
        p = fmaf(fmaxf(a3.y + q3.y, 0.f), w3.y, p);
        p = fmaf(fmaxf(a3.z + q3.z, 0.f), w3.z, p);
        p = fmaf(fmaxf(a3.w + q3.w, 0.f), w3.w, p);
        #pragma unroll
        for (int off = 1; off < 16; off <<= 1)
            p += __shfl_xor(p, off, 64);
        if (c == 0)
            out[(b * V_ + i) * V_ + j] = 1.f / (1.f + __builtin_expf(-(p + bo0)));
    }
}

// ---------------------------------------------------------------------------
extern "C" void kernel_launch(void* const* d_in, const int* in_sizes, int n_in,
                              void* d_out, int out_size, void* d_ws, size_t ws_size,
                              hipStream_t stream) {
    const int*   adj   = (const int*)  d_in[0];
    const float* xf    = (const float*)d_in[1];
    const float* ea    = (const float*)d_in[2];
    const float* ec1W1 = (const float*)d_in[3];
    const float* ec1b1 = (const float*)d_in[4];
    const float* ec1W2 = (const float*)d_in[5];
    const float* ec1b2 = (const float*)d_in[6];
    const float* ec2W1 = (const float*)d_in[7];
    const float* ec2b1 = (const float*)d_in[8];
    const float* ec2W2 = (const float*)d_in[9];
    const float* ec2b2 = (const float*)d_in[10];
    const float* h3W   = (const float*)d_in[11];
    const float* h3b   = (const float*)d_in[12];
    const float* oW    = (const float*)d_in[13];
    const float* ob    = (const float*)d_in[14];
    float* out = (float*)d_out;

    const int NV = B_ * V_;                        // 1024 nodes
    float* P1  = (float*)d_ws;                     // NV*H0
    float* Q1  = P1  + NV * H0_;
    float* P2  = Q1  + NV * H0_;
    float* Q2  = P2  + NV * H0_;
    float* Ai  = Q2  + NV * H0_;                   // NV*H2
    float* Aj  = Ai  + NV * H2_;
    float* WPT = Aj  + NV * H2_;                   // 128*128
    float* WQT = WPT + H0_ * H0_;                  // 128*128
    float* WJT = WQT + H0_ * H0_;                  // 256*128
    float* WIT = WJT + H2_ * H0_;                  // 256*128
    short* wsW = (short*)(WIT + H2_ * H0_);        // 40960 bf16
    short* W1cT1 = wsW;
    short* W2T1  = wsW + 4096;
    short* W1cT2 = wsW + 20480;
    short* W2T2  = wsW + 24576;

    // K1: conv1 hoist (256 blocks) + all weight prep (544 blocks)
    pre1_k<<<800, 256, 0, stream>>>(xf, ec1W1, ec1b1, P1, Q1,
                                    ec1W1 + 2 * C1_ * H0_, ec1W2,
                                    ec2W1 + 2 * H0_ * H0_, ec2W2,
                                    ec2W1, h3W,
                                    wsW, WPT, WQT, WJT, WIT);
    // K2: conv1 (dense MFMA) + fused conv2 hoist
    conv1_k<<<NV, 256, 0, stream>>>(adj, ea, P1, Q1, W1cT1, W2T1, ec1b2,
                                    WPT, WQT, ec2b1, P2, Q2);
    // K3: conv2 (dense MFMA) + fused pair hoist
    conv2_k<<<NV, 256, 0, stream>>>(adj, ea, P2, Q2, W1cT2, W2T2, ec2b2,
                                    WJT, WIT, h3b, Ai, Aj);
    // K4: pair output
    pair_out_k<<<256, 256, 0, stream>>>(Ai, Aj, oW, ob, out);
}

// Round 8
// 263.915 us; speedup vs baseline: 1.0853x; 1.0853x over previous
//
#include <hip/hip_runtime.h>
#include <hip/hip_bf16.h>
#include <math.h>

#define B_  4
#define V_  256
#define C1_ 64
#define C2_ 32
#define H0_ 128
#define H2_ 256

typedef short bf16x8 __attribute__((ext_vector_type(8)));
typedef float f32x4  __attribute__((ext_vector_type(4)));

static __device__ __forceinline__ short f2bf(float f) {
    unsigned u = __float_as_uint(f);
    u += 0x7fffu + ((u >> 16) & 1u);          // RNE
    return (short)(u >> 16);
}
// packed pair convert (v_cvt_pk path where available)
static __device__ __forceinline__ unsigned f2bf2(float x, float y) {
    float2 t; t.x = x; t.y = y;
    __hip_bfloat162 h = __float22bfloat162_rn(t);
    return *reinterpret_cast<unsigned*>(&h);
}

// ---------------------------------------------------------------------------
// Prep (K1, blocks >= 256): bf16+transpose MFMA weight fragments, and fp32
// transposed copies for the per-node fused tails.
//  wsW (shorts): W1cT1[4096] | W2T1[16384] | W1cT2[4096] | W2T2[16384]
//  WPT[n][k] = W1a2[k][n]-W1b2[k][n]; WQT[n][k] = W1b2[k][n]   (128x128)
//  WJT[n][k] = W3[k][n]; WIT[n][k] = W3[128+k][n]              (256x128)
// ---------------------------------------------------------------------------
static __device__ void prep_dev(int idx,
    const float* __restrict__ W1c1, const float* __restrict__ W21,
    const float* __restrict__ W1c2, const float* __restrict__ W22,
    const float* __restrict__ Wc2,  const float* __restrict__ W3,
    short* __restrict__ wsW, float* __restrict__ WPT, float* __restrict__ WQT,
    float* __restrict__ WJT, float* __restrict__ WIT)
{
    if (idx < 4096) {
        int n = idx >> 5, k = idx & 31;
        wsW[idx] = f2bf(W1c1[k * H0_ + n]);
    } else if (idx < 20480) {
        int t = idx - 4096; int n = t >> 7, k = t & 127;
        wsW[idx] = f2bf(W21[k * H0_ + n]);
    } else if (idx < 24576) {
        int t = idx - 20480; int n = t >> 5, k = t & 31;
        wsW[idx] = f2bf(W1c2[k * H0_ + n]);
    } else if (idx < 40960) {
        int t = idx - 24576; int n = t >> 7, k = t & 127;
        wsW[idx] = f2bf(W22[k * H0_ + n]);
    } else if (idx < 57344) {
        int t = idx - 40960; int n = t >> 7, k = t & 127;
        WPT[t] = Wc2[k * H0_ + n] - Wc2[(H0_ + k) * H0_ + n];
    } else if (idx < 73728) {
        int t = idx - 57344; int n = t >> 7, k = t & 127;
        WQT[t] = Wc2[(H0_ + k) * H0_ + n];
    } else if (idx < 106496) {
        int t = idx - 73728; int n = t >> 7, k = t & 127;
        WJT[t] = W3[k * H2_ + n];
    } else if (idx < 139264) {
        int t = idx - 106496; int n = t >> 7, k = t & 127;
        WIT[t] = W3[(H0_ + k) * H2_ + n];
    }
}

// ---------------------------------------------------------------------------
// Conv1 hoist, 4 nodes/block: P1 = x@(W1a-W1b)+b1, Q1 = x@W1b.
// ---------------------------------------------------------------------------
template <int CIN>
static __device__ void node_pre4(int g,
    const float* __restrict__ x, const float* __restrict__ W1,
    const float* __restrict__ b1, float* __restrict__ P, float* __restrict__ Q)
{
    const int bi0 = g * 4;
    const int tid = threadIdx.x;
    const int n   = tid & 127;
    const bool isP = tid < 128;             // wave-uniform split

    __shared__ __align__(16) float s_x4[4][CIN];
    for (int idx = tid; idx < 4 * CIN; idx += 256)
        s_x4[idx / CIN][idx % CIN] = x[bi0 * CIN + idx];
    __syncthreads();

    float acc[4];
    float binit = isP ? b1[n] : 0.f;
    #pragma unroll
    for (int nd = 0; nd < 4; ++nd) acc[nd] = binit;

    #pragma unroll 4
    for (int k = 0; k < CIN; k += 4) {
        float4 wv;
        if (isP) {
            wv.x = W1[(k + 0) * H0_ + n] - W1[(CIN + k + 0) * H0_ + n];
            wv.y = W1[(k + 1) * H0_ + n] - W1[(CIN + k + 1) * H0_ + n];
            wv.z = W1[(k + 2) * H0_ + n] - W1[(CIN + k + 2) * H0_ + n];
            wv.w = W1[(k + 3) * H0_ + n] - W1[(CIN + k + 3) * H0_ + n];
        } else {
            wv.x = W1[(CIN + k + 0) * H0_ + n];
            wv.y = W1[(CIN + k + 1) * H0_ + n];
            wv.z = W1[(CIN + k + 2) * H0_ + n];
            wv.w = W1[(CIN + k + 3) * H0_ + n];
        }
        #pragma unroll
        for (int nd = 0; nd < 4; ++nd) {
            float4 xv = *reinterpret_cast<const float4*>(&s_x4[nd][k]);
            acc[nd] = fmaf(xv.x, wv.x, acc[nd]);
            acc[nd] = fmaf(xv.y, wv.y, acc[nd]);
            acc[nd] = fmaf(xv.z, wv.z, acc[nd]);
            acc[nd] = fmaf(xv.w, wv.w, acc[nd]);
        }
    }
    float* dst = isP ? P : Q;
    #pragma unroll
    for (int nd = 0; nd < 4; ++nd)
        dst[(bi0 + nd) * H0_ + n] = acc[nd];
}

__global__ __launch_bounds__(256) void pre1_k(
    const float* __restrict__ xf, const float* __restrict__ ec1W1,
    const float* __restrict__ ec1b1, float* __restrict__ P1, float* __restrict__ Q1,
    const float* __restrict__ W1c1, const float* __restrict__ W21,
    const float* __restrict__ W1c2, const float* __restrict__ W22,
    const float* __restrict__ Wc2,  const float* __restrict__ W3,
    short* __restrict__ wsW, float* __restrict__ WPT, float* __restrict__ WQT,
    float* __restrict__ WJT, float* __restrict__ WIT)
{
    if (blockIdx.x < 256)
        node_pre4<C1_>(blockIdx.x, xf, ec1W1, ec1b1, P1, Q1);
    else
        prep_dev((blockIdx.x - 256) * 256 + threadIdx.x,
                 W1c1, W21, W1c2, W22, Wc2, W3, wsW, WPT, WQT, WJT, WIT);
}

// ---------------------------------------------------------------------------
// Dense EdgeConvE for ONE node, BARRIER-FREE inner loop (R3's wave-private
// pattern + R4's transposed GEMM1). Block = 1 node, 4 waves; wave w owns
// edges {c*64 + w*16 + l15}, c=0..3 -- its own 16 h1 rows in LDS, its own
// vmax for ALL 128 neurons. A1/B2 fragments are read from GLOBAL each use
// (40 KB shared by every block -> L1-hot) so VGPR stays low and 4 blocks/CU
// co-reside with no __launch_bounds__ spill. One __syncthreads at the end
// for the cross-wave max combine.
// ---------------------------------------------------------------------------
static __device__ void conv_node(int bi,
    const int* __restrict__ adj, const float* __restrict__ e,
    const float* __restrict__ P, const float* __restrict__ Q,
    const short* __restrict__ W1cT, const short* __restrict__ W2T,
    const float* __restrict__ b2,
    short (*s_h1)[136], float (*s_m)[H0_], float* s_x)
{
    const int b    = bi >> 8;
    const int tid  = threadIdx.x;
    const int w    = tid >> 6;
    const int lane = tid & 63;
    const int l15  = lane & 15;
    const int quad = lane >> 4;

    const float* __restrict__ ebase = e + (size_t)bi * V_ * C2_;
    const float* __restrict__ Pr    = P + bi * H0_;

    float vmax[8];
    #pragma unroll
    for (int nt = 0; nt < 8; ++nt) vmax[nt] = -1e30f;

    // prefetch chunk 0's e
    float4 e0 = *(const float4*)(ebase + (w * 16 + l15) * C2_ + quad * 8);
    float4 e1 = *(const float4*)(ebase + (w * 16 + l15) * C2_ + quad * 8 + 4);

    for (int c = 0; c < 4; ++c) {
        const int jr = c * 64 + w * 16 + l15;      // this lane's edge col

        // ---- GEMM1 (M=neurons, N=16 edges): Bf = e-frag ----
        int4 bfi;
        bfi.x = f2bf2(e0.x, e0.y);  bfi.y = f2bf2(e0.z, e0.w);
        bfi.z = f2bf2(e1.x, e1.y);  bfi.w = f2bf2(e1.z, e1.w);
        bf16x8 Bf = *reinterpret_cast<bf16x8*>(&bfi);

        const float* __restrict__ Qr = Q + (b * V_ + jr) * H0_;
        short* __restrict__ dst = &s_h1[w * 16 + l15][0];
        #pragma unroll
        for (int nt = 0; nt < 8; ++nt) {
            bf16x8 A1 = *(const bf16x8*)(W1cT + (nt * 16 + l15) * C2_ + quad * 8);
            f32x4 c4 = *(const f32x4*)(Pr + nt * 16 + quad * 4)
                     + *(const f32x4*)(Qr + nt * 16 + quad * 4);
            f32x4 a = __builtin_amdgcn_mfma_f32_16x16x32_bf16(A1, Bf, c4, 0, 0, 0);
            int2 hv;
            hv.x = f2bf2(fmaxf(a[0], 0.f), fmaxf(a[1], 0.f));
            hv.y = f2bf2(fmaxf(a[2], 0.f), fmaxf(a[3], 0.f));
            *(int2*)(dst + nt * 16 + quad * 4) = hv;
        }

        // prefetch next chunk's e (hides under GEMM2)
        if (c < 3) {
            const int jn = (c + 1) * 64 + w * 16 + l15;
            e0 = *(const float4*)(ebase + jn * C2_ + quad * 8);
            e1 = *(const float4*)(ebase + jn * C2_ + quad * 8 + 4);
        }

        // ---- GEMM2 (M = this wave's 16 edges, N = 128 neurons) ----
        // A2 rows are wave-private (written above by this same wave);
        // lgkmcnt ordering within the wave makes this safe without barriers.
        bf16x8 A2[4];
        #pragma unroll
        for (int kk = 0; kk < 4; ++kk)
            A2[kk] = *(const bf16x8*)(&s_h1[w * 16 + l15][kk * 32 + quad * 8]);

        const int4 av = *(const int4*)(adj + bi * V_ + c * 64 + w * 16 + quad * 4);

        #pragma unroll
        for (int nt = 0; nt < 8; ++nt) {
            f32x4 acc2 = {0.f, 0.f, 0.f, 0.f};
            #pragma unroll
            for (int kk = 0; kk < 4; ++kk) {
                bf16x8 B2 = *(const bf16x8*)(W2T + (nt * 16 + l15) * H0_ + kk * 32 + quad * 8);
                acc2 = __builtin_amdgcn_mfma_f32_16x16x32_bf16(A2[kk], B2, acc2, 0, 0, 0);
            }
            float m0 = av.x > 0 ? acc2[0] : -1e30f;
            float m1 = av.y > 0 ? acc2[1] : -1e30f;
            float m2 = av.z > 0 ? acc2[2] : -1e30f;
            float m3 = av.w > 0 ? acc2[3] : -1e30f;
            vmax[nt] = fmaxf(vmax[nt], fmaxf(fmaxf(m0, m1), fmaxf(m2, m3)));
        }
    }

    // cross-quad (edge rows) max inside the wave, then cross-wave via LDS
    #pragma unroll
    for (int nt = 0; nt < 8; ++nt) {
        float p = vmax[nt];
        p = fmaxf(p, __shfl_xor(p, 16, 64));
        p = fmaxf(p, __shfl_xor(p, 32, 64));
        if (quad == 0) s_m[w][nt * 16 + l15] = p;
    }
    __syncthreads();
    if (tid < H0_) {
        float m = fmaxf(fmaxf(s_m[0][tid], s_m[1][tid]),
                        fmaxf(s_m[2][tid], s_m[3][tid]));
        s_x[tid] = fmaxf(m + b2[tid], 0.f);      // isolated node -> 0
    }
    __syncthreads();
}

// ---------------------------------------------------------------------------
// Conv1 + fused conv2-hoist tail: P2 = x1@(W1a2-W1b2)+b1_2, Q2 = x1@W1b2.
// ---------------------------------------------------------------------------
__global__ __launch_bounds__(256) void conv1_k(
    const int* __restrict__ adj, const float* __restrict__ e,
    const float* __restrict__ P1, const float* __restrict__ Q1,
    const short* __restrict__ W1cT, const short* __restrict__ W2T,
    const float* __restrict__ b2,
    const float* __restrict__ WPT, const float* __restrict__ WQT,
    const float* __restrict__ b1_2,
    float* __restrict__ P2, float* __restrict__ Q2)
{
    __shared__ __align__(16) short s_h1[64][136];
    __shared__ __align__(16) float s_m[4][H0_];
    __shared__ __align__(16) float s_x[H0_];

    const int bi = blockIdx.x;
    conv_node(bi, adj, e, P1, Q1, W1cT, W2T, b2, s_h1, s_m, s_x);

    const int tid = threadIdx.x, n = tid & 127;
    const bool isP = tid < 128;
    const float* wrow = (isP ? WPT : WQT) + n * H0_;
    float acc = isP ? b1_2[n] : 0.f;
    #pragma unroll 4
    for (int k = 0; k < H0_; k += 4) {
        float4 x = *(const float4*)(s_x + k);
        float4 a = *(const float4*)(wrow + k);
        acc = fmaf(x.x, a.x, acc);
        acc = fmaf(x.y, a.y, acc);
        acc = fmaf(x.z, a.z, acc);
        acc = fmaf(x.w, a.w, acc);
    }
    if (isP) P2[bi * H0_ + n] = acc;
    else     Q2[bi * H0_ + n] = acc;
}

// ---------------------------------------------------------------------------
// Conv2 + fused pair-hoist tail: Ai = x2@W3[H0:]+b3, Aj = x2@W3[:H0].
// ---------------------------------------------------------------------------
__global__ __launch_bounds__(256) void conv2_k(
    const int* __restrict__ adj, const float* __restrict__ e,
    const float* __restrict__ P2, const float* __restrict__ Q2,
    const short* __restrict__ W1cT, const short* __restrict__ W2T,
    const float* __restrict__ b2,
    const float* __restrict__ WJT, const float* __restrict__ WIT,
    const float* __restrict__ b3,
    float* __restrict__ Ai, float* __restrict__ Aj)
{
    __shared__ __align__(16) short s_h1[64][136];
    __shared__ __align__(16) float s_m[4][H0_];
    __shared__ __align__(16) float s_x[H0_];

    const int bi = blockIdx.x;
    conv_node(bi, adj, e, P2, Q2, W1cT, W2T, b2, s_h1, s_m, s_x);

    const int n = threadIdx.x;                 // 0..255
    float aI = b3[n], aJ = 0.f;
    const float* wj = WJT + n * H0_;
    const float* wi = WIT + n * H0_;
    #pragma unroll 4
    for (int k = 0; k < H0_; k += 4) {
        float4 x  = *(const float4*)(s_x + k);
        float4 vj = *(const float4*)(wj + k);
        float4 vi = *(const float4*)(wi + k);
        aJ = fmaf(x.x, vj.x, aJ);  aI = fmaf(x.x, vi.x, aI);
        aJ = fmaf(x.y, vj.y, aJ);  aI = fmaf(x.y, vi.y, aI);
        aJ = fmaf(x.z, vj.z, aJ);  aI = fmaf(x.z, vi.z, aI);
        aJ = fmaf(x.w, vj.w, aJ);  aI = fmaf(x.w, vi.w, aI);
    }
    Ai[bi * H2_ + n] = aI;
    Aj[bi * H2_ + n] = aJ;
}

// ---------------------------------------------------------------------------
// Pair output: 512 blocks, 2 i's per block; waves (0,1)->i0, (2,3)->i1; each
// wave covers 128 j's. Aj rows software-pipelined (prefetch next j-group).
// ---------------------------------------------------------------------------
__global__ __launch_bounds__(256) void pair_out_k(
    const float* __restrict__ Ai, const float* __restrict__ Aj,
    const float* __restrict__ Wo, const float* __restrict__ bo,
    float* __restrict__ out)
{
    const int blk  = blockIdx.x;                   // 512 blocks
    const int b    = blk >> 7;
    const int w    = threadIdx.x >> 6;
    const int lane = threadIdx.x & 63;
    const int i    = ((blk & 127) << 1) + (w >> 1);
    const int jbase = (w & 1) * 128;
    const int jj   = lane >> 4;
    const int c    = lane & 15;

    const float* ai = Ai + (b * V_ + i) * H2_ + c * 16;
    float4 a0 = *(const float4*)(ai);
    float4 a1 = *(const float4*)(ai + 4);
    float4 a2 = *(const float4*)(ai + 8);
    float4 a3 = *(const float4*)(ai + 12);
    const float* wo = Wo + c * 16;
    float4 w0 = *(const float4*)(wo);
    float4 w1 = *(const float4*)(wo + 4);
    float4 w2 = *(const float4*)(wo + 8);
    float4 w3 = *(const float4*)(wo + 12);
    const float bo0 = bo[0];

    // prefetch first j-group
    const float* aj = Aj + (b * V_ + jbase + jj) * H2_ + c * 16;
    float4 q0 = *(const float4*)(aj);
    float4 q1 = *(const float4*)(aj + 4);
    float4 q2 = *(const float4*)(aj + 8);
    float4 q3 = *(const float4*)(aj + 12);

    for (int j0 = jbase; j0 < jbase + 128; j0 += 4) {
        float4 c0 = q0, c1 = q1, c2 = q2, c3 = q3;
        if (j0 + 4 < jbase + 128) {
            const float* ajn = Aj + (b * V_ + j0 + 4 + jj) * H2_ + c * 16;
            q0 = *(const float4*)(ajn);
            q1 = *(const float4*)(ajn + 4);
            q2 = *(const float4*)(ajn + 8);
            q3 = *(const float4*)(ajn + 12);
        }
        float p;
        p = fmaxf(a0.x + c0.x, 0.f) * w0.x;
        p = fmaf(fmaxf(a0.y + c0.y, 0.f), w0.y, p);
        p = fmaf(fmaxf(a0.z + c0.z, 0.f), w0.z, p);
        p = fmaf(fmaxf(a0.w + c0.w, 0.f), w0.w, p);
        p = fmaf(fmaxf(a1.x + c1.x, 0.f), w1.x, p);
        p = fmaf(fmaxf(a1.y + c1.y, 0.f), w1.y, p);
        p = fmaf(fmaxf(a1.z + c1.z, 0.f), w1.z, p);
        p = fmaf(fmaxf(a1.w + c1.w, 0.f), w1.w, p);
        p = fmaf(fmaxf(a2.x + c2.x, 0.f), w2.x, p);
        p = fmaf(fmaxf(a2.y + c2.y, 0.f), w2.y, p);
        p = fmaf(fmaxf(a2.z + c2.z, 0.f), w2.z, p);
        p = fmaf(fmaxf(a2.w + c2.w, 0.f), w2.w, p);
        p = fmaf(fmaxf(a3.x + c3.x, 0.f), w3.x, p);
        p = fmaf(fmaxf(a3.y + c3.y, 0.f), w3.y, p);
        p = fmaf(fmaxf(a3.z + c3.z, 0.f), w3.z, p);
        p = fmaf(fmaxf(a3.w + c3.w, 0.f), w3.w, p);
        #pragma unroll
        for (int off = 1; off < 16; off <<= 1)
            p += __shfl_xor(p, off, 64);
        if (c == 0)
            out[(b * V_ + i) * V_ + (j0 + jj)] =
                1.f / (1.f + __builtin_expf(-(p + bo0)));
    }
}

// ---------------------------------------------------------------------------
extern "C" void kernel_launch(void* const* d_in, const int* in_sizes, int n_in,
                              void* d_out, int out_size, void* d_ws, size_t ws_size,
                              hipStream_t stream) {
    const int*   adj   = (const int*)  d_in[0];
    const float* xf    = (const float*)d_in[1];
    const float* ea    = (const float*)d_in[2];
    const float* ec1W1 = (const float*)d_in[3];
    const float* ec1b1 = (const float*)d_in[4];
    const float* ec1W2 = (const float*)d_in[5];
    const float* ec1b2 = (const float*)d_in[6];
    const float* ec2W1 = (const float*)d_in[7];
    const float* ec2b1 = (const float*)d_in[8];
    const float* ec2W2 = (const float*)d_in[9];
    const float* ec2b2 = (const float*)d_in[10];
    const float* h3W   = (const float*)d_in[11];
    const float* h3b   = (const float*)d_in[12];
    const float* oW    = (const float*)d_in[13];
    const float* ob    = (const float*)d_in[14];
    float* out = (float*)d_out;

    const int NV = B_ * V_;                        // 1024 nodes
    float* P1  = (float*)d_ws;                     // NV*H0
    float* Q1  = P1  + NV * H0_;
    float* P2  = Q1  + NV * H0_;
    float* Q2  = P2  + NV * H0_;
    float* Ai  = Q2  + NV * H0_;                   // NV*H2
    float* Aj  = Ai  + NV * H2_;
    float* WPT = Aj  + NV * H2_;                   // 128*128
    float* WQT = WPT + H0_ * H0_;                  // 128*128
    float* WJT = WQT + H0_ * H0_;                  // 256*128
    float* WIT = WJT + H2_ * H0_;                  // 256*128
    short* wsW = (short*)(WIT + H2_ * H0_);        // 40960 bf16
    short* W1cT1 = wsW;
    short* W2T1  = wsW + 4096;
    short* W1cT2 = wsW + 20480;
    short* W2T2  = wsW + 24576;

    // K1: conv1 hoist (256 blocks) + all weight prep (544 blocks)
    pre1_k<<<800, 256, 0, stream>>>(xf, ec1W1, ec1b1, P1, Q1,
                                    ec1W1 + 2 * C1_ * H0_, ec1W2,
                                    ec2W1 + 2 * H0_ * H0_, ec2W2,
                                    ec2W1, h3W,
                                    wsW, WPT, WQT, WJT, WIT);
    // K2: conv1 (dense MFMA, barrier-free) + fused conv2 hoist
    conv1_k<<<NV, 256, 0, stream>>>(adj, ea, P1, Q1, W1cT1, W2T1, ec1b2,
                                    WPT, WQT, ec2b1, P2, Q2);
    // K3: conv2 (dense MFMA, barrier-free) + fused pair hoist
    conv2_k<<<NV, 256, 0, stream>>>(adj, ea, P2, Q2, W1cT2, W2T2, ec2b2,
                                    WJT, WIT, h3b, Ai, Aj);
    // K4: pair output (pipelined)
    pair_out_k<<<512, 256, 0, stream>>>(Ai, Aj, oW, ob, out);
}